// Round 1
// baseline (132.608 us; speedup 1.0000x reference)
//
#include <hip/hip_runtime.h>
#include <hip/hip_bf16.h>

#define NB 16
#define NC 128
#define NN 2048
#define NF 64
#define NEG_SLOPE 0.33f
#define MASK_VAL (-9.0e15f)

typedef float    f32x4 __attribute__((ext_vector_type(4)));
typedef _Float16 f16x4 __attribute__((ext_vector_type(4)));
typedef _Float16 f16x8 __attribute__((ext_vector_type(8)));

__device__ __forceinline__ float lrelu(float x) {
    return x > 0.0f ? x : x * NEG_SLOPE;
}

// Kernel 1: Wh = h^T @ W in fp32 (VALU, LDS-tiled); emit WhT f16 [b][f][n],
// s1 = Wh@a1, s2 = Wh@a2 in fp32.
__global__ __launch_bounds__(256) void k_precompute(
    const float* __restrict__ h, const float* __restrict__ W,
    const float* __restrict__ a, _Float16* __restrict__ wht,
    float* __restrict__ s1g, float* __restrict__ s2g)
{
    __shared__ float Wl[64 * 64];   // one 64-row half of W at a time (16 KB)
    __shared__ float ht[64 * 129];  // h tile transposed [n_local][c], padded (33 KB)

    const int t = threadIdx.x;
    const int b = blockIdx.x >> 5;
    const int n0 = (blockIdx.x & 31) << 6;
    const int lane = t & 63, cg = t >> 6;

    #pragma unroll 8
    for (int k = 0; k < 32; ++k) {
        const int c = cg * 32 + k;
        ht[lane * 129 + c] = h[(size_t)(b * NC + c) * NN + n0 + lane];
    }

    const int fg = t & 15, ns = t >> 4;   // f-group (4 f's), n-group (4 n's)
    f32x4 acc[4] = {};
    for (int half = 0; half < 2; ++half) {
        if (half) __syncthreads();        // protect Wl overwrite
        #pragma unroll
        for (int k = 0; k < 4; ++k) {
            const int idx = k * 1024 + t * 4;
            *(f32x4*)&Wl[idx] = *(const f32x4*)&W[half * 4096 + idx];
        }
        __syncthreads();                  // Wl (and ht on first iter) ready
        #pragma unroll 4
        for (int c2 = 0; c2 < 64; ++c2) {
            const f32x4 wv = *(const f32x4*)&Wl[c2 * 64 + fg * 4];
            #pragma unroll
            for (int m = 0; m < 4; ++m) {
                const float hv = ht[(ns * 4 + m) * 129 + half * 64 + c2];
                acc[m] += wv * hv;
            }
        }
    }

    const f32x4 a1v = *(const f32x4*)&a[fg * 4];
    const f32x4 a2v = *(const f32x4*)&a[NF + fg * 4];
    #pragma unroll
    for (int m = 0; m < 4; ++m) {
        float p1 = acc[m].x * a1v.x + acc[m].y * a1v.y + acc[m].z * a1v.z + acc[m].w * a1v.w;
        float p2 = acc[m].x * a2v.x + acc[m].y * a2v.y + acc[m].z * a2v.z + acc[m].w * a2v.w;
        #pragma unroll
        for (int d = 1; d < 16; d <<= 1) {   // reduce across the 16 f-groups
            p1 += __shfl_xor(p1, d, 64);
            p2 += __shfl_xor(p2, d, 64);
        }
        if (fg == 0) {
            const int n = n0 + ns * 4 + m;
            s1g[(size_t)b * NN + n] = p1;
            s2g[(size_t)b * NN + n] = p2;
        }
    }
    #pragma unroll
    for (int q = 0; q < 4; ++q) {
        f16x4 v;
        v[0] = (_Float16)acc[0][q]; v[1] = (_Float16)acc[1][q];
        v[2] = (_Float16)acc[2][q]; v[3] = (_Float16)acc[3][q];
        const int f = fg * 4 + q;
        *(f16x4*)&wht[((size_t)b * NF + f) * NN + n0 + ns * 4] = v;
    }
}

// Kernel 2: per (batch, 16-row tile): stream g once (mask -> ballot bits in LDS),
// row max, then chunked {p -> f16 LDS -> 16x16x32 f16 MFMA vs WhT}.
__global__ __launch_bounds__(512, 6) void k_attn(
    const float* __restrict__ g, const _Float16* __restrict__ wht,
    const float* __restrict__ s1g, const float* __restrict__ s2g,
    float* __restrict__ out)
{
    __shared__ float s2b[NN];                  // 8 KB
    __shared__ float s1b[16];
    __shared__ float Srow[16];
    __shared__ unsigned long long mb[16 * 32]; // mask bits: 16 rows x 2048 bits (4 KB)
    __shared__ _Float16 Pc[16 * 264];          // P chunk, padded stride (8.25 KB)
    __shared__ float scratch[1024];            // cross-wave acc reduce (4 KB)

    const int t = threadIdx.x;
    const int lane = t & 63;
    const int w = t >> 6;                      // wave 0..7
    const int b = blockIdx.x >> 7;
    const int i0 = (blockIdx.x & 127) << 4;

    *(f32x4*)&s2b[t * 4] = *(const f32x4*)&s2g[(size_t)b * NN + t * 4];
    if (t < 16) s1b[t] = s1g[(size_t)b * NN + i0 + t];
    __syncthreads();

    // ---- pass A: stream g row once, row max + mask bits (wave w owns rows w, w+8) ----
    const float* gb = g + (size_t)b * NN * NN;
    float mrow[2], s1r[2];
    #pragma unroll
    for (int rr = 0; rr < 2; ++rr) {
        const int r = w + rr * 8;
        const float* grow = gb + (size_t)(i0 + r) * NN;
        s1r[rr] = s1b[r];
        float m = MASK_VAL;
        #pragma unroll
        for (int tt = 0; tt < 8; ++tt) {
            const int j = tt * 256 + lane * 4;
            f32x4 gv = *(const f32x4*)&grow[j];
            f32x4 sv = *(const f32x4*)&s2b[j];
            #pragma unroll
            for (int u = 0; u < 4; ++u) {
                const bool on = gv[u] > 0.0f;
                const float e = on ? lrelu(s1r[rr] + sv[u]) : MASK_VAL;
                m = fmaxf(m, e);
                const unsigned long long bal = __ballot(on);
                if (lane == 0) mb[r * 32 + tt * 4 + u] = bal;
            }
        }
        #pragma unroll
        for (int d = 1; d < 64; d <<= 1) m = fmaxf(m, __shfl_xor(m, d, 64));
        mrow[rr] = m;
    }
    // mb rows are produced and consumed by the same wave -> no barrier needed here

    // ---- chunked pass B + PV MFMA ----
    const int nt = w & 3, kh = w >> 2;         // n-tile, k-half roles
    const int arow = lane & 15;
    const int koff = (lane >> 4) * 8;
    const _Float16* wb = wht + ((size_t)b * NF + nt * 16 + arow) * NN;
    float sumr[2] = {0.0f, 0.0f};
    f32x4 acc = {0.0f, 0.0f, 0.0f, 0.0f};

    for (int ch = 0; ch < 8; ++ch) {
        #pragma unroll
        for (int rr = 0; rr < 2; ++rr) {
            const int r = w + rr * 8;
            const int j = ch * 256 + lane * 4;
            f32x4 sv = *(const f32x4*)&s2b[j];
            f16x4 pv;
            #pragma unroll
            for (int u = 0; u < 4; ++u) {
                const unsigned long long wu = mb[r * 32 + ch * 4 + u];
                const bool on = (wu >> lane) & 1ull;
                const float e = on ? lrelu(s1r[rr] + sv[u]) : MASK_VAL;
                const float p = __expf(e - mrow[rr]);
                sumr[rr] += p;
                pv[u] = (_Float16)p;
            }
            *(f16x4*)&Pc[r * 264 + lane * 4] = pv;
        }
        __syncthreads();                        // Pc ready for all waves
        const _Float16* wbc = wb + ch * 256;
        #pragma unroll
        for (int ks = 0; ks < 4; ++ks) {
            const int kc = kh * 128 + ks * 32;
            f16x8 af = *(const f16x8*)&Pc[arow * 264 + kc + koff];
            f16x8 bf = *(const f16x8*)&wbc[kc + koff];
            acc = __builtin_amdgcn_mfma_f32_16x16x32_f16(af, bf, acc, 0, 0, 0);
        }
        __syncthreads();                        // protect Pc overwrite next chunk
    }

    // ---- row sums, cross-wave acc reduce, epilogue ----
    #pragma unroll
    for (int rr = 0; rr < 2; ++rr) {
        float s = sumr[rr];
        #pragma unroll
        for (int d = 1; d < 64; d <<= 1) s += __shfl_xor(s, d, 64);
        if (lane == 0) Srow[w + rr * 8] = s;
    }
    if (kh == 1) *(f32x4*)&scratch[(nt * 64 + lane) * 4] = acc;
    __syncthreads();
    if (kh == 0) {
        f32x4 o = *(const f32x4*)&scratch[(nt * 64 + lane) * 4];
        acc += o;
        const int rbase = (lane >> 4) * 4;      // D row = (lane>>4)*4 + reg (m89-verified)
        f32x4 res;
        #pragma unroll
        for (int r2 = 0; r2 < 4; ++r2) res[r2] = acc[r2] * (1.0f / Srow[rbase + r2]);
        const int f = nt * 16 + arow;           // D col = lane&15
        *(f32x4*)&out[((size_t)b * NF + f) * NN + (size_t)(i0 + rbase)] = res;
    }
}

extern "C" void kernel_launch(void* const* d_in, const int* in_sizes, int n_in,
                              void* d_out, int out_size, void* d_ws, size_t ws_size,
                              hipStream_t stream)
{
    (void)in_sizes; (void)n_in; (void)out_size; (void)ws_size;
    const float* h = (const float*)d_in[0];
    const float* g = (const float*)d_in[1];
    const float* W = (const float*)d_in[2];
    const float* a = (const float*)d_in[3];
    float* out = (float*)d_out;

    // workspace: WhT f16 (4 MiB) | s1 (128 KiB) | s2 (128 KiB)  -> ~4.45 MiB total
    char* ws = (char*)d_ws;
    _Float16* wht = (_Float16*)ws;
    float* s1 = (float*)(ws + (size_t)NB * NF * NN * sizeof(_Float16));
    float* s2 = s1 + (size_t)NB * NN;

    k_precompute<<<NB * (NN / 64), 256, 0, stream>>>(h, W, a, wht, s1, s2);
    k_attn<<<NB * (NN / 16), 512, 0, stream>>>(g, wht, s1, s2, out);
}

// Round 2
// 105.173 us; speedup vs baseline: 1.2609x; 1.2609x over previous
//
#include <hip/hip_runtime.h>
#include <hip/hip_bf16.h>

#define NB 16
#define NC 128
#define NN 2048
#define NF 64
#define NEG_SLOPE 0.33f
#define MASK_VAL (-9.0e15f)

typedef float    f32x4 __attribute__((ext_vector_type(4)));
typedef _Float16 f16x4 __attribute__((ext_vector_type(4)));
typedef _Float16 f16x8 __attribute__((ext_vector_type(8)));

__device__ __forceinline__ float lrelu(float x) {
    return x > 0.0f ? x : x * NEG_SLOPE;
}

// Kernel 1: Wh = h^T @ W in fp32 (VALU, LDS-tiled); emit WhT f16 [b][f][n],
// s1 = Wh@a1, s2 = Wh@a2 in fp32.  (unchanged from R0)
__global__ __launch_bounds__(256) void k_precompute(
    const float* __restrict__ h, const float* __restrict__ W,
    const float* __restrict__ a, _Float16* __restrict__ wht,
    float* __restrict__ s1g, float* __restrict__ s2g)
{
    __shared__ float Wl[64 * 64];
    __shared__ float ht[64 * 129];

    const int t = threadIdx.x;
    const int b = blockIdx.x >> 5;
    const int n0 = (blockIdx.x & 31) << 6;
    const int lane = t & 63, cg = t >> 6;

    #pragma unroll 8
    for (int k = 0; k < 32; ++k) {
        const int c = cg * 32 + k;
        ht[lane * 129 + c] = h[(size_t)(b * NC + c) * NN + n0 + lane];
    }

    const int fg = t & 15, ns = t >> 4;
    f32x4 acc[4] = {};
    for (int half = 0; half < 2; ++half) {
        if (half) __syncthreads();
        #pragma unroll
        for (int k = 0; k < 4; ++k) {
            const int idx = k * 1024 + t * 4;
            *(f32x4*)&Wl[idx] = *(const f32x4*)&W[half * 4096 + idx];
        }
        __syncthreads();
        #pragma unroll 4
        for (int c2 = 0; c2 < 64; ++c2) {
            const f32x4 wv = *(const f32x4*)&Wl[c2 * 64 + fg * 4];
            #pragma unroll
            for (int m = 0; m < 4; ++m) {
                const float hv = ht[(ns * 4 + m) * 129 + half * 64 + c2];
                acc[m] += wv * hv;
            }
        }
    }

    const f32x4 a1v = *(const f32x4*)&a[fg * 4];
    const f32x4 a2v = *(const f32x4*)&a[NF + fg * 4];
    #pragma unroll
    for (int m = 0; m < 4; ++m) {
        float p1 = acc[m].x * a1v.x + acc[m].y * a1v.y + acc[m].z * a1v.z + acc[m].w * a1v.w;
        float p2 = acc[m].x * a2v.x + acc[m].y * a2v.y + acc[m].z * a2v.z + acc[m].w * a2v.w;
        #pragma unroll
        for (int d = 1; d < 16; d <<= 1) {
            p1 += __shfl_xor(p1, d, 64);
            p2 += __shfl_xor(p2, d, 64);
        }
        if (fg == 0) {
            const int n = n0 + ns * 4 + m;
            s1g[(size_t)b * NN + n] = p1;
            s2g[(size_t)b * NN + n] = p2;
        }
    }
    #pragma unroll
    for (int q = 0; q < 4; ++q) {
        f16x4 v;
        v[0] = (_Float16)acc[0][q]; v[1] = (_Float16)acc[1][q];
        v[2] = (_Float16)acc[2][q]; v[3] = (_Float16)acc[3][q];
        const int f = fg * 4 + q;
        *(f16x4*)&wht[((size_t)b * NF + f) * NN + n0 + ns * 4] = v;
    }
}

// Kernel 2 (rewritten): single-pass online-softmax flash-style GAT.
// Per block: 16 query rows. 8 chunks of 256 j. Per chunk:
//   P-gen (each wave owns rows w, w+8): e -> running max -> alpha -> p(f16) -> Pc dbuf
//   barrier -> acc *= alpha[row]; 4x mfma_f32_16x16x32_f16 vs wht.
// g is streamed exactly once, continuously; next chunk's g prefetched in regs.
__global__ __launch_bounds__(512, 8) void k_attn(
    const float* __restrict__ g, const _Float16* __restrict__ wht,
    const float* __restrict__ s1g, const float* __restrict__ s2g,
    float* __restrict__ out)
{
    __shared__ float s2b[NN];                   // 8 KB
    __shared__ float s1b[16];
    __shared__ float Srow[16];
    __shared__ float alphaL[2 * 16];            // dbuf alpha
    __shared__ _Float16 Pc[2 * 16 * 264];       // dbuf P chunk, padded stride (16.5 KB)
    __shared__ float scratch[1024];             // cross-wave acc reduce (4 KB)

    const int t = threadIdx.x;
    const int lane = t & 63;
    const int w = t >> 6;                       // wave 0..7
    const int b = blockIdx.x >> 7;
    const int i0 = (blockIdx.x & 127) << 4;

    *(f32x4*)&s2b[t * 4] = *(const f32x4*)&s2g[(size_t)b * NN + t * 4];
    if (t < 16) s1b[t] = s1g[(size_t)b * NN + i0 + t];
    __syncthreads();

    const float* gb = g + (size_t)b * NN * NN;
    const float* gr0 = gb + (size_t)(i0 + w) * NN + lane * 4;
    const float* gr1 = gr0 + 8 * NN;
    const float s1r0 = s1b[w];
    const float s1r1 = s1b[w + 8];

    const int nt = w & 3, kh = w >> 2;          // MFMA roles: n-tile, k-half
    const int arow = lane & 15;
    const int koff = (lane >> 4) * 8;
    const _Float16* wb = wht + ((size_t)b * NF + nt * 16 + arow) * NN;

    float m0 = MASK_VAL, m1 = MASK_VAL;         // running row maxes
    float su0 = 0.0f, su1 = 0.0f;               // running (rescaled) row sums, per-lane partial
    f32x4 acc = {0.0f, 0.0f, 0.0f, 0.0f};

    f32x4 c0 = *(const f32x4*)gr0;              // prefetch chunk 0
    f32x4 c1 = *(const f32x4*)gr1;

    for (int ch = 0; ch < 8; ++ch) {
        f32x4 n0 = c0, n1 = c1;
        if (ch < 7) {                           // prefetch next chunk (HBM latency hides under compute)
            n0 = *(const f32x4*)(gr0 + (ch + 1) * 256);
            n1 = *(const f32x4*)(gr1 + (ch + 1) * 256);
        }
        const int pb = (ch & 1) * 16 * 264;
        const f32x4 sv = *(const f32x4*)&s2b[ch * 256 + lane * 4];

        // ---- row w (data c0) ----
        {
            float e0 = c0.x > 0.0f ? lrelu(s1r0 + sv.x) : MASK_VAL;
            float e1 = c0.y > 0.0f ? lrelu(s1r0 + sv.y) : MASK_VAL;
            float e2 = c0.z > 0.0f ? lrelu(s1r0 + sv.z) : MASK_VAL;
            float e3 = c0.w > 0.0f ? lrelu(s1r0 + sv.w) : MASK_VAL;
            float cm = fmaxf(fmaxf(e0, e1), fmaxf(e2, e3));
            #pragma unroll
            for (int d = 1; d < 64; d <<= 1) cm = fmaxf(cm, __shfl_xor(cm, d, 64));
            const float mn = fmaxf(m0, cm);
            const float al = __expf(m0 - mn);   // ==1 when max unchanged (exp(0))
            m0 = mn;
            const float p0 = __expf(e0 - mn), p1 = __expf(e1 - mn);
            const float p2 = __expf(e2 - mn), p3 = __expf(e3 - mn);
            su0 = su0 * al + ((p0 + p1) + (p2 + p3));
            f16x4 pv; pv[0] = (_Float16)p0; pv[1] = (_Float16)p1;
            pv[2] = (_Float16)p2; pv[3] = (_Float16)p3;
            *(f16x4*)&Pc[pb + w * 264 + lane * 4] = pv;
            if (lane == 0) alphaL[(ch & 1) * 16 + w] = al;
        }
        // ---- row w+8 (data c1) ----
        {
            float e0 = c1.x > 0.0f ? lrelu(s1r1 + sv.x) : MASK_VAL;
            float e1 = c1.y > 0.0f ? lrelu(s1r1 + sv.y) : MASK_VAL;
            float e2 = c1.z > 0.0f ? lrelu(s1r1 + sv.z) : MASK_VAL;
            float e3 = c1.w > 0.0f ? lrelu(s1r1 + sv.w) : MASK_VAL;
            float cm = fmaxf(fmaxf(e0, e1), fmaxf(e2, e3));
            #pragma unroll
            for (int d = 1; d < 64; d <<= 1) cm = fmaxf(cm, __shfl_xor(cm, d, 64));
            const float mn = fmaxf(m1, cm);
            const float al = __expf(m1 - mn);
            m1 = mn;
            const float p0 = __expf(e0 - mn), p1 = __expf(e1 - mn);
            const float p2 = __expf(e2 - mn), p3 = __expf(e3 - mn);
            su1 = su1 * al + ((p0 + p1) + (p2 + p3));
            f16x4 pv; pv[0] = (_Float16)p0; pv[1] = (_Float16)p1;
            pv[2] = (_Float16)p2; pv[3] = (_Float16)p3;
            *(f16x4*)&Pc[pb + (w + 8) * 264 + lane * 4] = pv;
            if (lane == 0) alphaL[(ch & 1) * 16 + w + 8] = al;
        }

        __syncthreads();   // Pc[pb] + alphaL ready; Pc[pb^1] now free to overwrite next iter

        // ---- MFMA phase: rescale acc by this chunk's alpha, then accumulate P*WhT ----
        {
            const f32x4 av = *(const f32x4*)&alphaL[(ch & 1) * 16 + (lane >> 4) * 4];
            acc.x *= av.x; acc.y *= av.y; acc.z *= av.z; acc.w *= av.w;
            const _Float16* wbc = wb + ch * 256;
            #pragma unroll
            for (int ks = 0; ks < 4; ++ks) {
                const int kc = kh * 128 + ks * 32;
                f16x8 af = *(const f16x8*)&Pc[pb + arow * 264 + kc + koff];
                f16x8 bf = *(const f16x8*)&wbc[kc + koff];
                acc = __builtin_amdgcn_mfma_f32_16x16x32_f16(af, bf, acc, 0, 0, 0);
            }
        }
        c0 = n0; c1 = n1;
    }

    // ---- row sums, cross-wave acc reduce, epilogue ----
    {
        float s = su0;
        #pragma unroll
        for (int d = 1; d < 64; d <<= 1) s += __shfl_xor(s, d, 64);
        if (lane == 0) Srow[w] = s;
        s = su1;
        #pragma unroll
        for (int d = 1; d < 64; d <<= 1) s += __shfl_xor(s, d, 64);
        if (lane == 0) Srow[w + 8] = s;
    }
    if (kh == 1) *(f32x4*)&scratch[(nt * 64 + lane) * 4] = acc;
    __syncthreads();
    if (kh == 0) {
        f32x4 o = *(const f32x4*)&scratch[(nt * 64 + lane) * 4];
        acc.x += o.x; acc.y += o.y; acc.z += o.z; acc.w += o.w;
        const int rbase = (lane >> 4) * 4;      // D row = (lane>>4)*4 + reg (m89-verified)
        f32x4 res;
        #pragma unroll
        for (int r2 = 0; r2 < 4; ++r2) res[r2] = acc[r2] * (1.0f / Srow[rbase + r2]);
        const int f = nt * 16 + arow;           // D col = lane&15
        *(f32x4*)&out[((size_t)b * NF + f) * NN + (size_t)(i0 + rbase)] = res;
    }
}

extern "C" void kernel_launch(void* const* d_in, const int* in_sizes, int n_in,
                              void* d_out, int out_size, void* d_ws, size_t ws_size,
                              hipStream_t stream)
{
    (void)in_sizes; (void)n_in; (void)out_size; (void)ws_size;
    const float* h = (const float*)d_in[0];
    const float* g = (const float*)d_in[1];
    const float* W = (const float*)d_in[2];
    const float* a = (const float*)d_in[3];
    float* out = (float*)d_out;

    // workspace: WhT f16 (4 MiB) | s1 (128 KiB) | s2 (128 KiB)
    char* ws = (char*)d_ws;
    _Float16* wht = (_Float16*)ws;
    float* s1 = (float*)(ws + (size_t)NB * NF * NN * sizeof(_Float16));
    float* s2 = s1 + (size_t)NB * NN;

    k_precompute<<<NB * (NN / 64), 256, 0, stream>>>(h, W, a, wht, s1, s2);
    k_attn<<<NB * (NN / 16), 512, 0, stream>>>(g, wht, s1, s2, out);
}